// Round 2
// baseline (2505.032 us; speedup 1.0000x reference)
//
#include <hip/hip_runtime.h>

#define Tt 8192     // tokens B*S
#define Dd 2048     // model dim
#define Ee 8        // routed experts
#define Hh 1368     // hidden
#define Hp 1408     // hidden padded to 44*32 = 11*128

using short8  = __attribute__((ext_vector_type(8))) short;
using float4v = __attribute__((ext_vector_type(4))) float;

__device__ __forceinline__ unsigned short f2b(float f) {
  union { float f; unsigned u; } v; v.f = f;
  unsigned r = v.u + 0x7fffu + ((v.u >> 16) & 1u);
  return (unsigned short)(r >> 16);
}

// load 8 consecutive fp32, round-to-nearest-even to bf16, pack as short8
__device__ __forceinline__ short8 load_cvt8(const float* g) {
  const float4* p = (const float4*)g;
  float4 a = p[0], b = p[1];
  short8 r;
  unsigned short* q = (unsigned short*)&r;
  q[0] = f2b(a.x); q[1] = f2b(a.y); q[2] = f2b(a.z); q[3] = f2b(a.w);
  q[4] = f2b(b.x); q[5] = f2b(b.y); q[6] = f2b(b.z); q[7] = f2b(b.w);
  return r;
}

// ---------------- router: logits, softmax, top-2, append, aux accum ----------
__global__ __launch_bounds__(256) void router_kernel(
    const float* __restrict__ x, const float* __restrict__ rw,
    int* __restrict__ cursor, float* __restrict__ psum, int* __restrict__ t1cnt,
    int* __restrict__ tok_id, float* __restrict__ tok_w)
{
  const int lane = threadIdx.x & 63;
  const int wv   = threadIdx.x >> 6;
  const int t    = blockIdx.x * 4 + wv;
  const float* xr = x + (size_t)t * Dd;
  float acc[Ee];
#pragma unroll
  for (int e = 0; e < Ee; ++e) acc[e] = 0.f;
  for (int d = lane * 4; d < Dd; d += 256) {
    float4 xv = *(const float4*)(xr + d);
#pragma unroll
    for (int e = 0; e < Ee; ++e) {
      float4 wvv = *(const float4*)(rw + (size_t)e * Dd + d);
      acc[e] += xv.x * wvv.x + xv.y * wvv.y + xv.z * wvv.z + xv.w * wvv.w;
    }
  }
#pragma unroll
  for (int e = 0; e < Ee; ++e)
#pragma unroll
    for (int off = 32; off > 0; off >>= 1)
      acc[e] += __shfl_xor(acc[e], off, 64);

  if (lane == 0) {
    float mx = acc[0];
    for (int e = 1; e < Ee; ++e) mx = fmaxf(mx, acc[e]);
    float p[Ee]; float s = 0.f;
    for (int e = 0; e < Ee; ++e) { p[e] = __expf(acc[e] - mx); s += p[e]; }
    float inv = 1.f / s;
    for (int e = 0; e < Ee; ++e) { p[e] *= inv; atomicAdd(&psum[e], p[e]); }
    // top-1 / top-2 by logits, ties -> lowest index (strict >)
    int e0 = 0;
    for (int e = 1; e < Ee; ++e) if (acc[e] > acc[e0]) e0 = e;
    int e1 = (e0 == 0) ? 1 : 0;
    for (int e = 0; e < Ee; ++e) if (e != e0 && acc[e] > acc[e1]) e1 = e;
    atomicAdd(&t1cnt[e0], 1);
    int pos0 = atomicAdd(&cursor[e0], 1);
    tok_id[e0 * Tt + pos0] = t; tok_w[e0 * Tt + pos0] = p[e0];
    int pos1 = atomicAdd(&cursor[e1], 1);
    tok_id[e1 * Tt + pos1] = t; tok_w[e1 * Tt + pos1] = p[e1];
  }
}

// ---------------- prep: padded bases, pad entries, aux loss ------------------
__global__ void prep_kernel(const int* __restrict__ cursor, int* __restrict__ base,
                            const float* __restrict__ psum, const int* __restrict__ t1cnt,
                            int* __restrict__ tok_id, float* __restrict__ tok_w,
                            float* __restrict__ aux_out)
{
  const int tid = threadIdx.x;
  if (tid == 0) {
    int tot = 0;
    for (int e = 0; e < Ee; ++e) { base[e] = tot; tot += (cursor[e] + 127) & ~127; }
    base[Ee] = tot;
    float s = 0.f;
    for (int e = 0; e < Ee; ++e)
      s += ((float)t1cnt[e] / (float)Tt) * (psum[e] / (float)Tt);
    aux_out[0] = 0.01f * (float)Ee * s;
  }
  for (int e = 0; e < Ee; ++e) {
    int c  = cursor[e];
    int pc = (c + 127) & ~127;
    for (int i = c + tid; i < pc; i += 256) {
      tok_id[e * Tt + i] = 0; tok_w[e * Tt + i] = 0.f;
    }
  }
}

// ---------------- GEMM1: act = silu(x@w1^T) * (x@w3^T), bf16 out ------------
// grid (11, 64, 9): z = expert (8 = shared), y = token tile, x = H tile
__global__ __launch_bounds__(256) void gemm1_kernel(
    const float* __restrict__ x,
    const float* __restrict__ w1, const float* __restrict__ w3,
    const float* __restrict__ sw1, const float* __restrict__ sw3,
    const int* __restrict__ tok_id, const int* __restrict__ base,
    unsigned short* __restrict__ act_r, unsigned short* __restrict__ act_s)
{
  const int z  = blockIdx.z;
  const int m0 = blockIdx.y * 128;
  const int n0 = blockIdx.x * 128;
  const int tid = threadIdx.x;
  const float *w1p, *w3p;
  unsigned short* actp;
  int arow0, tokA0, tokA1;
  if (z < Ee) {
    int b0 = base[z], b1 = base[z + 1];
    if (m0 >= b1 - b0) return;
    arow0 = b0;
    w1p = w1 + (size_t)z * Hh * Dd;
    w3p = w3 + (size_t)z * Hh * Dd;
    actp = act_r;
    tokA0 = tok_id[z * Tt + m0 + (tid >> 2)];
    tokA1 = tok_id[z * Tt + m0 + (tid >> 2) + 64];
  } else {
    arow0 = 0; w1p = sw1; w3p = sw3; actp = act_s;
    tokA0 = m0 + (tid >> 2); tokA1 = tokA0 + 64;
  }
  __shared__ __align__(16) unsigned short lA [128 * 32];
  __shared__ __align__(16) unsigned short lB1[128 * 32];
  __shared__ __align__(16) unsigned short lB3[128 * 32];
  const int r0 = tid >> 2;
  const int c0 = (tid & 3) * 8;
  const float* gA0 = x + (size_t)tokA0 * Dd + c0;
  const float* gA1 = x + (size_t)tokA1 * Dd + c0;
  int hb0 = n0 + r0;      if (hb0 >= Hh) hb0 = Hh - 1;   // clamp; OOB cols zeroed in epilogue
  int hb1 = n0 + r0 + 64; if (hb1 >= Hh) hb1 = Hh - 1;
  const float* gB1a = w1p + (size_t)hb0 * Dd + c0;
  const float* gB1b = w1p + (size_t)hb1 * Dd + c0;
  const float* gB3a = w3p + (size_t)hb0 * Dd + c0;
  const float* gB3b = w3p + (size_t)hb1 * Dd + c0;

  const int lane = tid & 63;
  const int wvi  = tid >> 6;
  const int wm = (wvi >> 1) * 64;
  const int wn = (wvi & 1) * 64;
  const int fr = lane & 15;
  const int fk = (lane >> 4) * 8;

  float4v zero4 = {0.f, 0.f, 0.f, 0.f};
  float4v acc1[4][4], acc3[4][4];
#pragma unroll
  for (int i = 0; i < 4; ++i)
#pragma unroll
    for (int j = 0; j < 4; ++j) { acc1[i][j] = zero4; acc3[i][j] = zero4; }

  for (int k = 0; k < Dd; k += 32) {
    short8 a0  = load_cvt8(gA0 + k);
    short8 a1  = load_cvt8(gA1 + k);
    short8 b1a = load_cvt8(gB1a + k);
    short8 b1b = load_cvt8(gB1b + k);
    short8 b3a = load_cvt8(gB3a + k);
    short8 b3b = load_cvt8(gB3b + k);
    __syncthreads();
    *(short8*)&lA [ r0       * 32 + c0] = a0;
    *(short8*)&lA [(r0 + 64) * 32 + c0] = a1;
    *(short8*)&lB1[ r0       * 32 + c0] = b1a;
    *(short8*)&lB1[(r0 + 64) * 32 + c0] = b1b;
    *(short8*)&lB3[ r0       * 32 + c0] = b3a;
    *(short8*)&lB3[(r0 + 64) * 32 + c0] = b3b;
    __syncthreads();
    short8 af[4], b1f[4], b3f[4];
#pragma unroll
    for (int i = 0; i < 4; ++i)
      af[i] = *(const short8*)&lA[(wm + i * 16 + fr) * 32 + fk];
#pragma unroll
    for (int j = 0; j < 4; ++j) {
      b1f[j] = *(const short8*)&lB1[(wn + j * 16 + fr) * 32 + fk];
      b3f[j] = *(const short8*)&lB3[(wn + j * 16 + fr) * 32 + fk];
    }
#pragma unroll
    for (int i = 0; i < 4; ++i)
#pragma unroll
      for (int j = 0; j < 4; ++j) {
        acc1[i][j] = __builtin_amdgcn_mfma_f32_16x16x32_bf16(af[i], b1f[j], acc1[i][j], 0, 0, 0);
        acc3[i][j] = __builtin_amdgcn_mfma_f32_16x16x32_bf16(af[i], b3f[j], acc3[i][j], 0, 0, 0);
      }
  }
  const int lr = (lane >> 4) * 4;
  const int lc = lane & 15;
#pragma unroll
  for (int i = 0; i < 4; ++i) {
#pragma unroll
    for (int r = 0; r < 4; ++r) {
      int slot = m0 + wm + i * 16 + lr + r;
      size_t arow = (size_t)(arow0 + slot) * Hp;
#pragma unroll
      for (int j = 0; j < 4; ++j) {
        int h = n0 + wn + j * 16 + lc;
        float g = acc1[i][j][r];
        float u = acc3[i][j][r];
        float val = (h < Hh) ? (g / (1.f + __expf(-g))) * u : 0.f;  // zero-fill pad cols
        actp[arow + h] = f2b(val);
      }
    }
  }
}

// ---------------- GEMM2: out += w * (act @ w2^T), atomic fp32 into d_out -----
// grid (16, 64, 9)
__global__ __launch_bounds__(256) void gemm2_kernel(
    const unsigned short* __restrict__ act_r, const unsigned short* __restrict__ act_s,
    const float* __restrict__ w2, const float* __restrict__ sw2,
    const int* __restrict__ tok_id, const float* __restrict__ tok_w,
    const int* __restrict__ base, float* __restrict__ out_f)
{
  const int z  = blockIdx.z;
  const int m0 = blockIdx.y * 128;
  const int d0 = blockIdx.x * 128;
  const int tid = threadIdx.x;
  const unsigned short* ap;
  const float* w2p;
  int arow0;
  if (z < Ee) {
    int b0 = base[z], b1 = base[z + 1];
    if (m0 >= b1 - b0) return;
    arow0 = b0; ap = act_r; w2p = w2 + (size_t)z * Dd * Hh;
  } else {
    arow0 = 0; ap = act_s; w2p = sw2;
  }
  __shared__ __align__(16) unsigned short lA[128 * 32];
  __shared__ __align__(16) unsigned short lB[128 * 32];
  const int r0 = tid >> 2;
  const int c0 = (tid & 3) * 8;
  const unsigned short* gA0 = ap + (size_t)(arow0 + m0 + r0) * Hp + c0;
  const unsigned short* gA1 = ap + (size_t)(arow0 + m0 + r0 + 64) * Hp + c0;
  const float* gB0 = w2p + (size_t)(d0 + r0) * Hh;
  const float* gB1 = w2p + (size_t)(d0 + r0 + 64) * Hh;

  const int lane = tid & 63;
  const int wvi  = tid >> 6;
  const int wm = (wvi >> 1) * 64;
  const int wn = (wvi & 1) * 64;
  const int fr = lane & 15;
  const int fk = (lane >> 4) * 8;

  float4v zero4 = {0.f, 0.f, 0.f, 0.f};
  float4v acc[4][4];
#pragma unroll
  for (int i = 0; i < 4; ++i)
#pragma unroll
    for (int j = 0; j < 4; ++j) acc[i][j] = zero4;

  for (int k = 0; k < Hp; k += 32) {
    int kc = k + c0; if (kc > Hh - 8) kc = Hh - 8;  // clamp; A cols >= Hh are zero
    short8 a0 = *(const short8*)(gA0 + k);
    short8 a1 = *(const short8*)(gA1 + k);
    short8 b0 = load_cvt8(gB0 + kc);
    short8 b1 = load_cvt8(gB1 + kc);
    __syncthreads();
    *(short8*)&lA[ r0       * 32 + c0] = a0;
    *(short8*)&lA[(r0 + 64) * 32 + c0] = a1;
    *(short8*)&lB[ r0       * 32 + c0] = b0;
    *(short8*)&lB[(r0 + 64) * 32 + c0] = b1;
    __syncthreads();
    short8 af[4], bf[4];
#pragma unroll
    for (int i = 0; i < 4; ++i)
      af[i] = *(const short8*)&lA[(wm + i * 16 + fr) * 32 + fk];
#pragma unroll
    for (int j = 0; j < 4; ++j)
      bf[j] = *(const short8*)&lB[(wn + j * 16 + fr) * 32 + fk];
#pragma unroll
    for (int i = 0; i < 4; ++i)
#pragma unroll
      for (int j = 0; j < 4; ++j)
        acc[i][j] = __builtin_amdgcn_mfma_f32_16x16x32_bf16(af[i], bf[j], acc[i][j], 0, 0, 0);
  }
  const int lr = (lane >> 4) * 4;
  const int lc = lane & 15;
#pragma unroll
  for (int i = 0; i < 4; ++i) {
#pragma unroll
    for (int r = 0; r < 4; ++r) {
      int slot = m0 + wm + i * 16 + lr + r;
      int tok; float wgt;
      if (z < Ee) { tok = tok_id[z * Tt + slot]; wgt = tok_w[z * Tt + slot]; }
      else        { tok = slot; wgt = 1.f; }
      float* orow = out_f + (size_t)tok * Dd + d0 + wn + lc;
#pragma unroll
      for (int j = 0; j < 4; ++j)
        atomicAdd(orow + j * 16, acc[i][j][r] * wgt);
    }
  }
}

extern "C" void kernel_launch(void* const* d_in, const int* in_sizes, int n_in,
                              void* d_out, int out_size, void* d_ws, size_t ws_size,
                              hipStream_t stream)
{
  const float* x   = (const float*)d_in[0];
  const float* rw  = (const float*)d_in[1];
  const float* w1  = (const float*)d_in[2];
  const float* w2  = (const float*)d_in[3];
  const float* w3  = (const float*)d_in[4];
  const float* sw1 = (const float*)d_in[5];
  const float* sw2 = (const float*)d_in[6];
  const float* sw3 = (const float*)d_in[7];

  char* ws = (char*)d_ws;
  // layout: [0,32) cursor, [64,100) base, [128,160) psum, [160,192) t1cnt
  int*   cursor = (int*)(ws + 0);
  int*   basep  = (int*)(ws + 64);
  float* psum   = (float*)(ws + 128);
  int*   t1cnt  = (int*)(ws + 160);
  int*   tok_id = (int*)(ws + 256);                          // E*T ints
  float* tok_w  = (float*)(ws + 256 + 262144);               // E*T floats
  unsigned short* act_r = (unsigned short*)(ws + 524544);    // 17408 * Hp bf16
  unsigned short* act_s = (unsigned short*)(ws + 524544 + 49020928);   // T * Hp bf16
  float* out_f = (float*)d_out;

  hipMemsetAsync(ws, 0, 256, stream);
  hipMemsetAsync(out_f, 0, (size_t)Tt * Dd * sizeof(float), stream);
  router_kernel<<<Tt / 4, 256, 0, stream>>>(x, rw, cursor, psum, t1cnt, tok_id, tok_w);
  prep_kernel<<<1, 256, 0, stream>>>(cursor, basep, psum, t1cnt, tok_id, tok_w,
                                     out_f + (size_t)Tt * Dd);
  gemm1_kernel<<<dim3(11, 64, 9), 256, 0, stream>>>(x, w1, w3, sw1, sw3,
                                                    tok_id, basep, act_r, act_s);
  gemm2_kernel<<<dim3(16, 64, 9), 256, 0, stream>>>(act_r, act_s, w2, sw2,
                                                    tok_id, tok_w, basep, out_f);
}